// Round 6
// baseline (689.743 us; speedup 1.0000x reference)
//
#include <hip/hip_runtime.h>
#include <hip/hip_bf16.h>

#define T_TOK 4096
#define H_DIM 2048
#define E_NUM 8
#define I_DIM 1408
#define RTOT  8192
#define N1DIM 2816          // gemm1 N (gate|up interleaved)
#define MAXMT 40
#define MAXROWS 10752
#define NT1   11
#define NKT1  64
#define NKT2  44
#define G1_BLOCKS 440       // 8 xcd * 5 mt * 11 nt
#define GU_BLOCKS 2816      // 32 kt * 11 cw * 8 e
#define DN_BLOCKS 1408      // 22 kt * 8 nw * 8 e  (folded into gemm1 tail)
#define RT_BLOCKS 1024
#define BLK1 180224         // 2816*64 ushorts per kt-slab of W1T
#define BLK2 131072         // 2048*64 ushorts per kt-slab of WdT

// both GEMMs: ring4 x (A 16KB + B 16KB) = 128 KB  (proven footprint)
#define BUF1U 16384         // ushorts per ring slot
#define LDS1  131072
#define LDSP  65536         // prep: 64k x 256c fp32 staging tile

typedef __bf16 bf16x8 __attribute__((ext_vector_type(8)));
typedef float  floatx4 __attribute__((ext_vector_type(4)));
typedef unsigned short ushortx8 __attribute__((ext_vector_type(8)));

#define VMCNT(n) asm volatile("s_waitcnt vmcnt(" #n ")" ::: "memory")
#define LGK0() do { asm volatile("s_waitcnt lgkmcnt(0)" ::: "memory"); __builtin_amdgcn_sched_barrier(0); } while(0)

__device__ __forceinline__ unsigned short f2bf(float f) {
  union { float f; unsigned u; } v; v.f = f;
  unsigned r = v.u + 0x7FFFu + ((v.u >> 16) & 1u);  // RNE
  return (unsigned short)(r >> 16);
}

__device__ __forceinline__ void async16(const void* g, void* l) {
  __builtin_amdgcn_global_load_lds(
      (__attribute__((address_space(1))) void*)(g),
      (__attribute__((address_space(3))) void*)(l), 16, 0, 0);
}

// ---------------- merged: router (blocks 0..1023) + gate_up convert (async16-staged) ----------
// W1T blocked layout: [e][kt=32][np=2816][64 k] bf16; np interleaves gate/up at 16-col granularity.
__global__ void prep_kernel(const float* __restrict__ W, unsigned short* __restrict__ W1T,
                            const float* __restrict__ x, const float* __restrict__ rw,
                            int* __restrict__ topk_idx, float* __restrict__ topk_w,
                            int* __restrict__ counts) {
  extern __shared__ float ft[];   // [64 k][256 c] fp32
  int bid = blockIdx.x;
  int tid = threadIdx.x;
  if (bid < RT_BLOCKS) {
    int wave = tid >> 6, lane = tid & 63;
    int tk = bid * 4 + wave;
    const float* xr = x + (size_t)tk * H_DIM;
    float acc[E_NUM];
#pragma unroll
    for (int e = 0; e < E_NUM; e++) acc[e] = 0.f;
    for (int h = lane; h < H_DIM; h += 64) {
      float xv = xr[h];
      const float* wr = rw + h * E_NUM;
#pragma unroll
      for (int e = 0; e < E_NUM; e++) acc[e] += xv * wr[e];
    }
#pragma unroll
    for (int e = 0; e < E_NUM; e++) {
      float v = acc[e];
#pragma unroll
      for (int s = 32; s > 0; s >>= 1) v += __shfl_xor(v, s, 64);
      acc[e] = v;
    }
    if (lane == 0) {
      float mx = acc[0];
#pragma unroll
      for (int e = 1; e < E_NUM; e++) mx = fmaxf(mx, acc[e]);
      float p[E_NUM], s = 0.f;
#pragma unroll
      for (int e = 0; e < E_NUM; e++) { p[e] = __expf(acc[e] - mx); s += p[e]; }
      float inv = 1.0f / s;
      int i0 = 0;
#pragma unroll
      for (int e = 1; e < E_NUM; e++) if (p[e] > p[i0]) i0 = e;
      int i1 = (i0 == 0) ? 1 : 0;
#pragma unroll
      for (int e = 0; e < E_NUM; e++) if (e != i0 && p[e] > p[i1]) i1 = e;
      topk_idx[tk * 2]     = i0;
      topk_idx[tk * 2 + 1] = i1;
      topk_w[tk * 2]       = p[i0] * inv;
      topk_w[tk * 2 + 1]   = p[i1] * inv;
      atomicAdd(&counts[i0], 1);
      atomicAdd(&counts[i1], 1);
    }
    return;
  }
  int b = bid - RT_BLOCKS;
  int kt = b & 31;                 // over H/64
  int cw = (b >> 5) % 11;          // 256-src-col window
  int e  = b / (32 * 11);
  int k0 = kt * 64, c0 = cw * 256;
  int lane = tid & 63, wave = tid >> 6;
  const float* srcb = W + ((size_t)e * H_DIM + k0) * (2 * I_DIM) + c0;
  // stage 64KB fp32 tile: 16 async16/thread, all in flight (row = wave + 4i, 1KB/instr coalesced)
#pragma unroll
  for (int i = 0; i < 16; i++) {
    int row = wave + 4 * i;
    async16(srcb + (size_t)row * (2 * I_DIM) + lane * 4,
            (char*)ft + ((size_t)tid + 256 * i) * 16);
  }
  VMCNT(0);
  __syncthreads();
  // phase 2: thread owns src col c=tid -> output row np (128B contiguous)
  int sc = c0 + tid;
  int np = (sc < I_DIM) ? (((sc >> 4) << 5) + (sc & 15))
                        : ((((sc - I_DIM) >> 4) << 5) + 16 + ((sc - I_DIM) & 15));
  unsigned short* Ob = W1T + ((size_t)e * 32 + kt) * BLK1 + (size_t)np * 64;
#pragma unroll
  for (int g = 0; g < 8; g++) {
    ushortx8 o;
#pragma unroll
    for (int j = 0; j < 8; j++) o[j] = f2bf(ft[(size_t)(g * 8 + j) * 256 + tid]);
    *(ushortx8*)(Ob + g * 8) = o;
  }
}

// ---------------- scan: single 256-row tile table ----------------
__global__ void scan_kernel(const int* __restrict__ counts, int* __restrict__ cursors,
                            int* __restrict__ t1e, int* __restrict__ t1m0, int* __restrict__ t1end) {
  if (threadIdx.x == 0) {
    int o = 0, n1t = 0;
    for (int e = 0; e < E_NUM; e++) {
      int c = counts[e];
      cursors[e] = o;
      int n1 = (c + 255) >> 8;
      for (int j = 0; j < n1; j++) { t1e[n1t] = e; t1m0[n1t] = o + 256 * j; t1end[n1t] = o + c; n1t++; }
      o += 256 * n1;
    }
    for (; n1t < MAXMT; n1t++) t1e[n1t] = -1;
  }
}

__global__ void assign_kernel(const int* __restrict__ topk_idx, int* __restrict__ cursors,
                              int* __restrict__ row_of, int* __restrict__ tok_of) {
  int i = blockIdx.x * blockDim.x + threadIdx.x;
  int e = topk_idx[i];
  int row = atomicAdd(&cursors[e], 1);
  row_of[i] = row;
  tok_of[row] = i >> 1;
}

// ---------------- gather: x -> Xp row-major bf16, padded rows clamped ----------------
__global__ void gather_kernel(const float* __restrict__ x, const int* __restrict__ tok_of,
                              const int* __restrict__ t1e, const int* __restrict__ t1m0,
                              const int* __restrict__ t1end, unsigned short* __restrict__ Xp) {
  int mt = blockIdx.x >> 8;
  if (t1e[mt] < 0) return;
  int r = blockIdx.x & 255;
  int row = t1m0[mt] + r;
  int end = t1end[mt];
  int rr = row < end ? row : end - 1;
  int tok = tok_of[rr];
  const float4* src = (const float4*)(x + (size_t)tok * H_DIM);
  int i = threadIdx.x;
  float4 v0 = src[i * 2], v1 = src[i * 2 + 1];
  ushortx8 o;
  o[0] = f2bf(v0.x); o[1] = f2bf(v0.y); o[2] = f2bf(v0.z); o[3] = f2bf(v0.w);
  o[4] = f2bf(v1.x); o[5] = f2bf(v1.y); o[6] = f2bf(v1.z); o[7] = f2bf(v1.w);
  *(ushortx8*)(Xp + (size_t)row * H_DIM + i * 8) = o;
}

// staging macros (names resolved in kernel scope)
#define STG_A(lb) do { async16(gA0, (lb) + dA0); gA0 += 32; async16(gA1, (lb) + dA1); gA1 += 32; } while(0)
#define STG_B(lb, inc) do { async16(gB0, (lb) + dB0); gB0 += (inc); async16(gB1, (lb) + dB1); gB1 += (inc); } while(0)

// ---------------- GEMM1 (+ folded dn-convert, async16-staged): 256x256, BK=32, ring-4 ----------
__global__ __launch_bounds__(512, 2) void gemm1_kernel(
    const unsigned short* __restrict__ Xp, const unsigned short* __restrict__ W1T,
    const float* __restrict__ Wdn, unsigned short* __restrict__ WdT,
    const int* __restrict__ t1e, const int* __restrict__ t1m0, const int* __restrict__ t1end,
    unsigned short* __restrict__ Hmid) {
  extern __shared__ unsigned short sm[];
  int bid = blockIdx.x;
  int tid = threadIdx.x;
  if (bid >= G1_BLOCKS) {
    // convert down (E,I,H) f32 -> WdT blocked [e][kt=22][n=2048][64] bf16, async16-staged
    float* ft = (float*)sm;         // [64 k][256 n] fp32 = 64 KB of the 128 KB dynamic LDS
    int db = bid - G1_BLOCKS;
    int kt = db % 22;                 // over I/64
    int nw = (db / 22) & 7;           // 256-col window over H
    int e  = db / (22 * 8);
    int k0 = kt * 64, n0w = nw * 256;
    int lane = tid & 63, wave = tid >> 6;
    const float* srcb = Wdn + (size_t)e * I_DIM * H_DIM + (size_t)k0 * H_DIM + n0w;
#pragma unroll
    for (int i = 0; i < 8; i++) {
      int row = wave + 8 * i;
      async16(srcb + (size_t)row * H_DIM + lane * 4,
              (char*)ft + ((size_t)tid + 512 * i) * 16);
    }
    VMCNT(0);
    __syncthreads();
    int n = tid & 255, kh = tid >> 8;   // kh 0..1 splits k-range
    unsigned short* Ob = WdT + ((size_t)e * 22 + kt) * BLK2 + (size_t)(n0w + n) * 64 + kh * 32;
#pragma unroll
    for (int g = 0; g < 4; g++) {
      ushortx8 o;
#pragma unroll
      for (int j = 0; j < 8; j++) o[j] = f2bf(ft[(size_t)(kh * 32 + g * 8 + j) * 256 + n]);
      *(ushortx8*)(Ob + g * 8) = o;
    }
    return;
  }
  int xcd = bid & 7, jj = bid >> 3;
  int mt = xcd * 5 + jj / NT1, nt = jj % NT1;
  int e = t1e[mt];
  if (e < 0) return;
  int m0 = t1m0[mt], rend = t1end[mt];
  int n0 = nt * 256;
  int wave = tid >> 6, lane = tid & 63;
  int wm = wave >> 2, wn = wave & 3;
  int l15 = lane & 15, qq = lane >> 4;

  // stage units: wave-contiguous, inverse-swizzled global source (rule 21)
  int u0 = wave * 128 + lane, u1 = u0 + 64;
  int r0 = u0 >> 2, s0 = (u0 & 3) ^ ((u0 >> 3) & 3);
  int r1 = u1 >> 2, s1 = (u1 & 3) ^ ((u1 >> 3) & 3);
  const unsigned short* gA0 = Xp + (size_t)(m0 + r0) * H_DIM + s0 * 8;
  const unsigned short* gA1 = Xp + (size_t)(m0 + r1) * H_DIM + s1 * 8;
  const unsigned short* gB0 = W1T + (size_t)e * N1DIM * H_DIM + (size_t)(n0 + r0) * 64 + s0 * 8;
  const unsigned short* gB1 = W1T + (size_t)e * N1DIM * H_DIM + (size_t)(n0 + r1) * 64 + s1 * 8;
  int dA0 = u0 * 8, dA1 = u1 * 8;
  int dB0 = 8192 + u0 * 8, dB1 = 8192 + u1 * 8;

  // swizzled ds_read bases (bytes): unit nibble = q ^ ((row>>1)&3)
  int sw = (qq ^ ((l15 >> 1) & 3)) * 16;
  int sA = (wm * 128 + l15) * 64 + sw;
  int sB = 16384 + (wn * 64 + l15) * 64 + sw;

  STG_A(sm); STG_B(sm, 32);
  { unsigned short* lb = sm + BUF1U; STG_A(lb); STG_B(lb, BLK1 - 32); }
  floatx4 acc[8][4] = {};
  VMCNT(4);
  __builtin_amdgcn_s_barrier();

  for (int t = 0; t < NKT1; t++) {
    const char* sb = (const char*)(sm + (t & 3) * BUF1U);
    unsigned short* lb = sm + ((t + 2) & 3) * BUF1U;
    bool pf = (t + 2 < NKT1);
    bf16x8 a[8], b0, b1, b2, b3;
#pragma unroll
    for (int fr = 0; fr < 8; fr++) a[fr] = *(const bf16x8*)(sb + sA + fr * 1024);
    b0 = *(const bf16x8*)(sb + sB);
    b1 = *(const bf16x8*)(sb + sB + 1024);
    if (pf) STG_A(lb);
    __builtin_amdgcn_s_barrier();
    LGK0();
    __builtin_amdgcn_s_setprio(1);
#pragma unroll
    for (int fr = 0; fr < 8; fr++) {
      acc[fr][0] = __builtin_amdgcn_mfma_f32_16x16x32_bf16(a[fr], b0, acc[fr][0], 0, 0, 0);
      acc[fr][1] = __builtin_amdgcn_mfma_f32_16x16x32_bf16(a[fr], b1, acc[fr][1], 0, 0, 0);
    }
    __builtin_amdgcn_s_setprio(0);
    __builtin_amdgcn_s_barrier();
    b2 = *(const bf16x8*)(sb + sB + 2048);
    b3 = *(const bf16x8*)(sb + sB + 3072);
    if (pf) { STG_B(lb, (t & 1) ? (BLK1 - 32) : 32); VMCNT(4); } else { VMCNT(0); }
    __builtin_amdgcn_s_barrier();
    LGK0();
    __builtin_amdgcn_s_setprio(1);
#pragma unroll
    for (int fr = 0; fr < 8; fr++) {
      acc[fr][2] = __builtin_amdgcn_mfma_f32_16x16x32_bf16(a[fr], b2, acc[fr][2], 0, 0, 0);
      acc[fr][3] = __builtin_amdgcn_mfma_f32_16x16x32_bf16(a[fr], b3, acc[fr][3], 0, 0, 0);
    }
    __builtin_amdgcn_s_setprio(0);
  }

  // epilogue: silu(gate)*up from (even,odd) ni pairs -> Hmid row-major [row][1408]
  int rb = wm * 128 + (lane >> 4) * 4;
  int lc0 = nt * 128 + wn * 32 + l15;
#pragma unroll
  for (int fr = 0; fr < 8; fr++) {
#pragma unroll
    for (int p = 0; p < 2; p++) {
      int lcol = lc0 + p * 16;
#pragma unroll
      for (int r = 0; r < 4; r++) {
        int arow = m0 + rb + fr * 16 + r;
        if (arow < rend) {
          float g = acc[fr][2 * p][r];
          float u = acc[fr][2 * p + 1][r];
          float s = g / (1.0f + __expf(-g));
          Hmid[(size_t)arow * I_DIM + lcol] = f2bf(s * u);
        }
      }
    }
  }
}

// ---------------- GEMM2: 256x256, BK=32, ring-4 (proven geometry, blocked B) ----------------
__global__ __launch_bounds__(512, 2) void gemm2_kernel(
    const unsigned short* __restrict__ Hmid, const unsigned short* __restrict__ WdT,
    const int* __restrict__ t1e, const int* __restrict__ t1m0, const int* __restrict__ t1end,
    float* __restrict__ H2) {
  extern __shared__ unsigned short sm[];
  int bid = blockIdx.x;
  int xcd = bid & 7, jj = bid >> 3;
  int mt = xcd * 5 + (jj >> 3), nt = jj & 7;
  int e = t1e[mt];
  if (e < 0) return;
  int m0 = t1m0[mt], rend = t1end[mt];
  int n0 = nt * 256;
  int tid = threadIdx.x, wave = tid >> 6, lane = tid & 63;
  int wm = wave >> 2, wn = wave & 3;
  int l15 = lane & 15, qq = lane >> 4;

  int u0 = wave * 128 + lane, u1 = u0 + 64;
  int r0 = u0 >> 2, s0 = (u0 & 3) ^ ((u0 >> 3) & 3);
  int r1 = u1 >> 2, s1 = (u1 & 3) ^ ((u1 >> 3) & 3);
  const unsigned short* gA0 = Hmid + (size_t)(m0 + r0) * I_DIM + s0 * 8;
  const unsigned short* gA1 = Hmid + (size_t)(m0 + r1) * I_DIM + s1 * 8;
  const unsigned short* gB0 = WdT + (size_t)e * H_DIM * I_DIM + (size_t)(n0 + r0) * 64 + s0 * 8;
  const unsigned short* gB1 = WdT + (size_t)e * H_DIM * I_DIM + (size_t)(n0 + r1) * 64 + s1 * 8;
  int dA0 = u0 * 8, dA1 = u1 * 8;
  int dB0 = 8192 + u0 * 8, dB1 = 8192 + u1 * 8;

  int sw = (qq ^ ((l15 >> 1) & 3)) * 16;
  int sA = (wm * 128 + l15) * 64 + sw;
  int sB = 16384 + (wn * 64 + l15) * 64 + sw;

  STG_A(sm); STG_B(sm, 32);
  { unsigned short* lb = sm + BUF1U; STG_A(lb); STG_B(lb, BLK2 - 32); }
  floatx4 acc[8][4] = {};
  VMCNT(4);
  __builtin_amdgcn_s_barrier();

  for (int t = 0; t < NKT2; t++) {
    const char* sb = (const char*)(sm + (t & 3) * BUF1U);
    unsigned short* lb = sm + ((t + 2) & 3) * BUF1U;
    bool pf = (t + 2 < NKT2);
    bf16x8 a[8], b0, b1, b2, b3;
#pragma unroll
    for (int fr = 0; fr < 8; fr++) a[fr] = *(const bf16x8*)(sb + sA + fr * 1024);
    b0 = *(const bf16x8*)(sb + sB);
    b1 = *(const bf16x8*)(sb + sB + 1024);
    if (pf) STG_A(lb);
    __builtin_amdgcn_s_barrier();
    LGK0();
    __builtin_amdgcn_s_setprio(1);
#pragma unroll
    for (int fr = 0; fr < 8; fr++) {
      acc[fr][0] = __builtin_amdgcn_mfma_f32_16x16x32_bf16(a[fr], b0, acc[fr][0], 0, 0, 0);
      acc[fr][1] = __builtin_amdgcn_mfma_f32_16x16x32_bf16(a[fr], b1, acc[fr][1], 0, 0, 0);
    }
    __builtin_amdgcn_s_setprio(0);
    __builtin_amdgcn_s_barrier();
    b2 = *(const bf16x8*)(sb + sB + 2048);
    b3 = *(const bf16x8*)(sb + sB + 3072);
    if (pf) { STG_B(lb, (t & 1) ? (BLK2 - 32) : 32); VMCNT(4); } else { VMCNT(0); }
    __builtin_amdgcn_s_barrier();
    LGK0();
    __builtin_amdgcn_s_setprio(1);
#pragma unroll
    for (int fr = 0; fr < 8; fr++) {
      acc[fr][2] = __builtin_amdgcn_mfma_f32_16x16x32_bf16(a[fr], b2, acc[fr][2], 0, 0, 0);
      acc[fr][3] = __builtin_amdgcn_mfma_f32_16x16x32_bf16(a[fr], b3, acc[fr][3], 0, 0, 0);
    }
    __builtin_amdgcn_s_setprio(0);
  }

  int rb = wm * 128 + (lane >> 4) * 4;
  int cb = n0 + wn * 64 + l15;
#pragma unroll
  for (int fr = 0; fr < 8; fr++) {
#pragma unroll
    for (int ni = 0; ni < 4; ni++) {
#pragma unroll
      for (int r = 0; r < 4; r++) {
        int arow = m0 + rb + fr * 16 + r;
        if (arow < rend) H2[(size_t)arow * H_DIM + cb + ni * 16] = acc[fr][ni][r];
      }
    }
  }
}

// ---------------- combine ----------------
__global__ void combine_kernel(const float* __restrict__ H2, const int* __restrict__ row_of,
                               const float* __restrict__ topk_w, float* __restrict__ out) {
  int t = blockIdx.x >> 1;
  int part = blockIdx.x & 1;
  int c = part * 1024 + threadIdx.x * 4;
  int r0 = row_of[t * 2], r1 = row_of[t * 2 + 1];
  float w0 = topk_w[t * 2], w1 = topk_w[t * 2 + 1];
  float4 a = *(const float4*)(H2 + (size_t)r0 * H_DIM + c);
  float4 b = *(const float4*)(H2 + (size_t)r1 * H_DIM + c);
  float4 o;
  o.x = w0 * a.x + w1 * b.x;
  o.y = w0 * a.y + w1 * b.y;
  o.z = w0 * a.z + w1 * b.z;
  o.w = w0 * a.w + w1 * b.w;
  *(float4*)(out + (size_t)t * H_DIM + c) = o;
}

extern "C" void kernel_launch(void* const* d_in, const int* in_sizes, int n_in,
                              void* d_out, int out_size, void* d_ws, size_t ws_size,
                              hipStream_t stream) {
  const float* x   = (const float*)d_in[0];
  const float* rw  = (const float*)d_in[1];
  const float* wgu = (const float*)d_in[2];
  const float* wdn = (const float*)d_in[3];
  float* out = (float*)d_out;

  static bool attr_done = false;
  if (!attr_done) {
    hipFuncSetAttribute(reinterpret_cast<const void*>(gemm1_kernel),
                        hipFuncAttributeMaxDynamicSharedMemorySize, LDS1);
    hipFuncSetAttribute(reinterpret_cast<const void*>(gemm2_kernel),
                        hipFuncAttributeMaxDynamicSharedMemorySize, LDS1);
    hipFuncSetAttribute(reinterpret_cast<const void*>(prep_kernel),
                        hipFuncAttributeMaxDynamicSharedMemorySize, LDSP);
    attr_done = true;
  }

  char* ws = (char*)d_ws;
  size_t off = 0;
  auto alloc = [&](size_t b) {
    char* p = ws + off;
    off = (off + b + 255) & ~(size_t)255;
    return p;
  };
  unsigned short* W1T  = (unsigned short*)alloc((size_t)E_NUM * N1DIM * H_DIM * 2);
  unsigned short* WdT  = (unsigned short*)alloc((size_t)E_NUM * H_DIM * I_DIM * 2);
  unsigned short* Xp   = (unsigned short*)alloc((size_t)MAXROWS * H_DIM * 2);
  unsigned short* Hmid = (unsigned short*)alloc((size_t)MAXROWS * I_DIM * 2);
  float* H2            = (float*)alloc((size_t)MAXROWS * H_DIM * 4);
  int*   topk_idx      = (int*)alloc(RTOT * 4);
  float* topk_w        = (float*)alloc(RTOT * 4);
  int*   row_of        = (int*)alloc(RTOT * 4);
  int*   tok_of        = (int*)alloc((size_t)MAXROWS * 4);
  int*   counts        = (int*)alloc(256);
  int*   cursors       = (int*)alloc(256);
  int*   t1e           = (int*)alloc(MAXMT * 4);
  int*   t1m0          = (int*)alloc(MAXMT * 4);
  int*   t1end         = (int*)alloc(MAXMT * 4);

  hipMemsetAsync(counts, 0, E_NUM * sizeof(int), stream);

  prep_kernel<<<RT_BLOCKS + GU_BLOCKS, 256, LDSP, stream>>>(wgu, W1T, x, rw, topk_idx, topk_w, counts);
  scan_kernel<<<1, 64, 0, stream>>>(counts, cursors, t1e, t1m0, t1end);
  assign_kernel<<<RTOT / 256, 256, 0, stream>>>(topk_idx, cursors, row_of, tok_of);
  gather_kernel<<<MAXMT * 256, 256, 0, stream>>>(x, tok_of, t1e, t1m0, t1end, Xp);
  gemm1_kernel<<<G1_BLOCKS + DN_BLOCKS, 512, LDS1, stream>>>(Xp, W1T, wdn, WdT, t1e, t1m0, t1end, Hmid);
  gemm2_kernel<<<320, 512, LDS1, stream>>>(Hmid, WdT, t1e, t1m0, t1end, H2);
  combine_kernel<<<T_TOK * 2, 256, 0, stream>>>(H2, row_of, topk_w, out);
}